// Round 1
// baseline (5187.152 us; speedup 1.0000x reference)
//
#include <hip/hip_runtime.h>
#include <hip/hip_bf16.h>
#include <math.h>

// Problem constants (fixed by setup_inputs)
constexpr int kB  = 4;
constexpr int kH  = 128;
constexpr int kW  = 128;
constexpr int kHW = kH * kW;          // 16384
constexpr int kC1 = 256;              // layer1 in channels
constexpr int kM  = 128;              // mid channels (layer1 out / layer2 in)
constexpr int kC2 = 256;              // layer2 out channels

// ---------------- weight pre-transpose kernels ----------------
// w_off (27, C, 3, 3)  ->  wofft[c][k][32] (padded, zeros past 27)
__global__ __launch_bounds__(256) void prep_wofft(const float* __restrict__ w,
                                                  float* __restrict__ wt, int C) {
  int i = blockIdx.x * 256 + threadIdx.x;
  int total = C * 9 * 32;
  if (i >= total) return;
  int oc = i & 31;
  int ck = i >> 5;
  int k = ck % 9;
  int c = ck / 9;
  wt[i] = (oc < 27) ? w[((size_t)oc * C + c) * 9 + k] : 0.f;
}

// w (O, C, 3, 3) -> wt[c][k][O]
__global__ __launch_bounds__(256) void prep_wt(const float* __restrict__ w,
                                               float* __restrict__ wt, int C, int O) {
  int i = blockIdx.x * 256 + threadIdx.x;
  int total = C * 9 * O;
  if (i >= total) return;
  int o = i % O;
  int ck = i / O;
  int k = ck % 9;
  int c = ck / 9;
  wt[i] = w[((size_t)o * C + c) * 9 + k];
}

// ---------------- offset conv (3x3, SAME, 27 outputs) ----------------
// grid: (64 tiles, B, CSPLIT) block (16,16). Atomic-accumulate into om (pre-zeroed).
template <int CIN, int CSPLIT>
__global__ __launch_bounds__(256) void offs_conv(const float* __restrict__ x,
                                                 const float* __restrict__ wofft,
                                                 float* __restrict__ om) {
  const int tx = threadIdx.x, ty = threadIdx.y;
  const int tile = blockIdx.x, b = blockIdx.y, cs = blockIdx.z;
  const int h0 = (tile >> 3) << 4, w0 = (tile & 7) << 4;
  const int h = h0 + ty, w = w0 + tx;
  __shared__ float xs[18][18];
  float acc[28];
#pragma unroll
  for (int i = 0; i < 28; i++) acc[i] = 0.f;
  const int CCH = CIN / CSPLIT;
  const int c0 = cs * CCH;
  for (int cc = 0; cc < CCH; cc++) {
    const int c = c0 + cc;
    const float* xc = x + ((size_t)(b * CIN + c)) * kHW;
    __syncthreads();
    for (int idx = ty * 16 + tx; idx < 324; idx += 256) {
      int iy = idx / 18;
      int ix = idx - iy * 18;
      int gy = h0 - 1 + iy, gx = w0 - 1 + ix;
      xs[iy][ix] = (gy >= 0 && gy < kH && gx >= 0 && gx < kW) ? xc[gy * kW + gx] : 0.f;
    }
    __syncthreads();
    float xv[9];
#pragma unroll
    for (int k = 0; k < 9; k++) xv[k] = xs[ty + k / 3][tx + k % 3];
    const float* wr = wofft + (size_t)c * 9 * 32;
#pragma unroll
    for (int k = 0; k < 9; k++) {
      const float4* wv = (const float4*)(wr + k * 32);
      float s = xv[k];
#pragma unroll
      for (int q = 0; q < 7; q++) {
        float4 ww = wv[q];
        acc[q * 4 + 0] = fmaf(s, ww.x, acc[q * 4 + 0]);
        acc[q * 4 + 1] = fmaf(s, ww.y, acc[q * 4 + 1]);
        acc[q * 4 + 2] = fmaf(s, ww.z, acc[q * 4 + 2]);
        acc[q * 4 + 3] = fmaf(s, ww.w, acc[q * 4 + 3]);
      }
    }
  }
  float* base = om + ((size_t)b * 27) * kHW + h * kW + w;
#pragma unroll
  for (int oc = 0; oc < 27; oc++) atomicAdd(base + (size_t)oc * kHW, acc[oc]);
}

// ---------------- fused DCN sample + main conv ----------------
// grid: (64 tiles, B, O/32) block (16,16); thread = 1 pixel x 32 out-channels.
template <int CIN>
__global__ __launch_bounds__(256) void dcn_conv(const float* __restrict__ x,
                                                const float* __restrict__ om,
                                                const float* __restrict__ boff,
                                                const float* __restrict__ wt,
                                                const float* __restrict__ bias,
                                                float* __restrict__ y, int O) {
  const int tx = threadIdx.x, ty = threadIdx.y;
  const int tile = blockIdx.x, b = blockIdx.y, oc0 = blockIdx.z * 32;
  const int h0 = (tile >> 3) << 4, w0 = (tile & 7) << 4;
  const int h = h0 + ty, w = w0 + tx;

  const float* omb = om + ((size_t)b * 27) * kHW + h * kW + w;
  int off00[9], off01[9], off10[9], off11[9];
  float wgt00[9], wgt01[9], wgt10[9], wgt11[9];
#pragma unroll
  for (int k = 0; k < 9; k++) {
    float offy = omb[(size_t)k * kHW] + boff[k];
    float offx = omb[(size_t)(9 + k) * kHW] + boff[9 + k];
    float ml = omb[(size_t)(18 + k) * kHW] + boff[18 + k];
    float mask = 1.f / (1.f + expf(-ml));
    float py = (float)(h + (k / 3) - 1) + offy;
    float px = (float)(w + (k % 3) - 1) + offx;
    float fy = floorf(py), fx = floorf(px);
    float ly = py - fy, lx = px - fx;
    int yi = (int)fy, xi = (int)fx;
    bool vy0 = (yi >= 0) & (yi < kH);
    bool vy1 = (yi + 1 >= 0) & (yi + 1 < kH);
    bool vx0 = (xi >= 0) & (xi < kW);
    bool vx1 = (xi + 1 >= 0) & (xi + 1 < kW);
    int y0c = min(max(yi, 0), kH - 1), y1c = min(max(yi + 1, 0), kH - 1);
    int x0c = min(max(xi, 0), kW - 1), x1c = min(max(xi + 1, 0), kW - 1);
    off00[k] = y0c * kW + x0c;
    off01[k] = y0c * kW + x1c;
    off10[k] = y1c * kW + x0c;
    off11[k] = y1c * kW + x1c;
    float m00 = (1.f - ly) * (1.f - lx), m01 = (1.f - ly) * lx;
    float m10 = ly * (1.f - lx), m11 = ly * lx;
    wgt00[k] = (vy0 && vx0) ? m00 * mask : 0.f;
    wgt01[k] = (vy0 && vx1) ? m01 * mask : 0.f;
    wgt10[k] = (vy1 && vx0) ? m10 * mask : 0.f;
    wgt11[k] = (vy1 && vx1) ? m11 * mask : 0.f;
  }

  float acc[32];
#pragma unroll
  for (int j = 0; j < 32; j++) acc[j] = 0.f;

  const float* xb = x + (size_t)b * CIN * kHW;
  for (int c = 0; c < CIN; c++) {
    const float* xc = xb + (size_t)c * kHW;
    float sv[9];
#pragma unroll
    for (int k = 0; k < 9; k++) {
      sv[k] = xc[off00[k]] * wgt00[k] + xc[off01[k]] * wgt01[k] +
              xc[off10[k]] * wgt10[k] + xc[off11[k]] * wgt11[k];
    }
    const float* wtc = wt + ((size_t)c * 9) * O + oc0;
#pragma unroll
    for (int k = 0; k < 9; k++) {
      const float4* wv = (const float4*)(wtc + (size_t)k * O);
      float s = sv[k];
#pragma unroll
      for (int q = 0; q < 8; q++) {
        float4 ww = wv[q];
        acc[q * 4 + 0] = fmaf(s, ww.x, acc[q * 4 + 0]);
        acc[q * 4 + 1] = fmaf(s, ww.y, acc[q * 4 + 1]);
        acc[q * 4 + 2] = fmaf(s, ww.z, acc[q * 4 + 2]);
        acc[q * 4 + 3] = fmaf(s, ww.w, acc[q * 4 + 3]);
      }
    }
  }
  float* yp = y + ((size_t)(b * O + oc0)) * kHW + h * kW + w;
#pragma unroll
  for (int j = 0; j < 32; j++) yp[(size_t)j * kHW] = acc[j] + bias[oc0 + j];
}

// ---------------- BN stats (one block per channel) ----------------
__global__ __launch_bounds__(256) void bn_stats(const float* __restrict__ y,
                                                const float* __restrict__ g,
                                                const float* __restrict__ be,
                                                float* __restrict__ ss, int C) {
  const int c = blockIdx.x;
  float s = 0.f, s2 = 0.f;
  for (int b = 0; b < kB; b++) {
    const float4* p = (const float4*)(y + ((size_t)(b * C + c)) * kHW);
    for (int i = threadIdx.x; i < kHW / 4; i += 256) {
      float4 v = p[i];
      s += v.x + v.y + v.z + v.w;
      s2 += v.x * v.x + v.y * v.y + v.z * v.z + v.w * v.w;
    }
  }
#pragma unroll
  for (int o = 32; o > 0; o >>= 1) {
    s += __shfl_down(s, o, 64);
    s2 += __shfl_down(s2, o, 64);
  }
  __shared__ float red[8];
  int lane = threadIdx.x & 63, wid = threadIdx.x >> 6;
  if (lane == 0) {
    red[wid] = s;
    red[4 + wid] = s2;
  }
  __syncthreads();
  if (threadIdx.x == 0) {
    float S = red[0] + red[1] + red[2] + red[3];
    float S2 = red[4] + red[5] + red[6] + red[7];
    const float inv = 1.f / (float)(kB * kHW);
    float mu = S * inv;
    float var = S2 * inv - mu * mu;
    float sc = g[c] * rsqrtf(var + 1e-5f);
    ss[2 * c] = sc;
    ss[2 * c + 1] = be[c] - mu * sc;
  }
}

// ---------------- BN apply + ReLU (elementwise, in-place safe) ----------------
__global__ __launch_bounds__(256) void bn_apply(const float* __restrict__ y,
                                                const float* __restrict__ ss,
                                                float* __restrict__ out, int C,
                                                int total4) {
  int idx = blockIdx.x * 256 + threadIdx.x;
  int stride = gridDim.x * 256;
  for (int i = idx; i < total4; i += stride) {
    int c = (i >> 12) % C;  // kHW/4 = 4096 = 2^12 float4 per channel-plane
    float sc = ss[2 * c], sh = ss[2 * c + 1];
    float4 v = ((const float4*)y)[i];
    v.x = fmaxf(fmaf(v.x, sc, sh), 0.f);
    v.y = fmaxf(fmaf(v.y, sc, sh), 0.f);
    v.z = fmaxf(fmaf(v.z, sc, sh), 0.f);
    v.w = fmaxf(fmaf(v.w, sc, sh), 0.f);
    ((float4*)out)[i] = v;
  }
}

// ---------------- launch ----------------
extern "C" void kernel_launch(void* const* d_in, const int* in_sizes, int n_in,
                              void* d_out, int out_size, void* d_ws, size_t ws_size,
                              hipStream_t stream) {
  const float* x      = (const float*)d_in[0];
  const float* w_off1 = (const float*)d_in[1];
  const float* b_off1 = (const float*)d_in[2];
  const float* w1     = (const float*)d_in[3];
  const float* b1     = (const float*)d_in[4];
  const float* g1     = (const float*)d_in[5];
  const float* be1    = (const float*)d_in[6];
  const float* w_off2 = (const float*)d_in[7];
  const float* b_off2 = (const float*)d_in[8];
  const float* w2     = (const float*)d_in[9];
  const float* b2     = (const float*)d_in[10];
  const float* g2     = (const float*)d_in[11];
  const float* be2    = (const float*)d_in[12];

  char* ws = (char*)d_ws;
  // workspace layout (bytes)
  const size_t OM_OFF = 0;                      // 27*B*HW*4      = 7,077,888
  const size_t OM_SZ  = (size_t)27 * kB * kHW * 4;
  const size_t H_OFF  = OM_OFF + OM_SZ;         // mid activations 33,554,432
  const size_t H_SZ   = (size_t)kB * kM * kHW * 4;
  const size_t WOFFT_OFF = H_OFF + H_SZ;        // 294,912
  const size_t WOFFT_SZ  = (size_t)kC1 * 9 * 32 * 4;
  const size_t WT_OFF = WOFFT_OFF + WOFFT_SZ;   // 1,179,648
  const size_t WT_SZ  = (size_t)kC1 * 9 * kM * 4;
  const size_t SS_OFF = WT_OFF + WT_SZ;         // 2 KB stats

  float* om    = (float*)(ws + OM_OFF);
  float* hbuf  = (float*)(ws + H_OFF);
  float* wofft = (float*)(ws + WOFFT_OFF);
  float* wt    = (float*)(ws + WT_OFF);
  float* ssb   = (float*)(ws + SS_OFF);
  float* ybuf  = (float*)d_out;  // y1 (32MB) then y2 (64MB) live in d_out

  dim3 blk2(16, 16);

  // ---------- layer 1 ----------
  prep_wofft<<<(kC1 * 9 * 32 + 255) / 256, 256, 0, stream>>>(w_off1, wofft, kC1);
  prep_wt<<<(kC1 * 9 * kM + 255) / 256, 256, 0, stream>>>(w1, wt, kC1, kM);
  hipMemsetAsync(om, 0, OM_SZ, stream);
  offs_conv<kC1, 4><<<dim3(64, kB, 4), blk2, 0, stream>>>(x, wofft, om);
  dcn_conv<kC1><<<dim3(64, kB, kM / 32), blk2, 0, stream>>>(x, om, b_off1, wt, b1,
                                                            ybuf, kM);
  bn_stats<<<kM, 256, 0, stream>>>(ybuf, g1, be1, ssb, kM);
  bn_apply<<<2048, 256, 0, stream>>>(ybuf, ssb, hbuf, kM, kB * kM * kHW / 4);

  // ---------- layer 2 ----------
  prep_wofft<<<(kM * 9 * 32 + 255) / 256, 256, 0, stream>>>(w_off2, wofft, kM);
  prep_wt<<<(kM * 9 * kC2 + 255) / 256, 256, 0, stream>>>(w2, wt, kM, kC2);
  hipMemsetAsync(om, 0, OM_SZ, stream);
  offs_conv<kM, 4><<<dim3(64, kB, 4), blk2, 0, stream>>>(hbuf, wofft, om);
  dcn_conv<kM><<<dim3(64, kB, kC2 / 32), blk2, 0, stream>>>(hbuf, om, b_off2, wt, b2,
                                                            ybuf, kC2);
  bn_stats<<<kC2, 256, 0, stream>>>(ybuf, g2, be2, ssb, kC2);
  bn_apply<<<2048, 256, 0, stream>>>(ybuf, ssb, (float*)d_out, kC2,
                                     kB * kC2 * kHW / 4);
}

// Round 2
// 659.937 us; speedup vs baseline: 7.8601x; 7.8601x over previous
//
#include <hip/hip_runtime.h>
#include <hip/hip_bf16.h>
#include <math.h>

// Problem constants (fixed by setup_inputs)
constexpr int kB  = 4;
constexpr int kH  = 128;
constexpr int kW  = 128;
constexpr int kHW = kH * kW;          // 16384
constexpr int kC1 = 256;              // layer1 in channels
constexpr int kM  = 128;              // mid channels
constexpr int kC2 = 256;              // layer2 out channels

typedef unsigned short u16;
typedef __attribute__((ext_vector_type(8))) short bf16x8;
typedef __attribute__((ext_vector_type(4))) float f32x4;

__device__ inline float bf2f(short s) {
  return __uint_as_float(((unsigned)(u16)s) << 16);
}
__device__ inline u16 f2bf(float f) {
  unsigned u = __float_as_uint(f);
  unsigned r = u + 0x7FFFu + ((u >> 16) & 1u);
  return (u16)(r >> 16);
}

// ---------------- NCHW f32 -> NHWC bf16 (optionally fused BN+ReLU) ----------
template <bool BN>
__global__ __launch_bounds__(256) void to_nhwc(const float* __restrict__ src,
                                               const float* __restrict__ ss,
                                               u16* __restrict__ dst, int C) {
  int pxg = blockIdx.x * 256 + threadIdx.x;  // 0 .. B*HW-1
  int b = pxg >> 14, p = pxg & 16383;
  const float* sp = src + (size_t)b * C * kHW + p;
  u16* dp = dst + (size_t)pxg * C;
  for (int c = 0; c < C; c += 2) {
    float v0 = sp[(size_t)c * kHW], v1 = sp[(size_t)(c + 1) * kHW];
    if (BN) {
      v0 = fmaxf(fmaf(v0, ss[2 * c], ss[2 * c + 1]), 0.f);
      v1 = fmaxf(fmaf(v1, ss[2 * c + 2], ss[2 * c + 3]), 0.f);
    }
    unsigned pk = (unsigned)f2bf(v0) | ((unsigned)f2bf(v1) << 16);
    *(unsigned*)(dp + c) = pk;
  }
}

// ------------- weight pre-pack into MFMA B-fragment order -------------------
// layout: [CIN/32][9][OPAD/16][64 lanes][8]  ; k_local = 8*(lane>>4)+j, n = 16*nt + (lane&15)
__global__ __launch_bounds__(256) void prep_bpack(const float* __restrict__ w,
                                                  u16* __restrict__ bp, int CIN,
                                                  int OPAD, int OREAL) {
  int i = blockIdx.x * 256 + threadIdx.x;
  int ntiles = OPAD / 16;
  int total = (CIN / 32) * 9 * ntiles * 64 * 8;
  if (i >= total) return;
  int j = i & 7, l = (i >> 3) & 63;
  int rest = i >> 9;
  int nt = rest % ntiles; rest /= ntiles;
  int tap = rest % 9;
  int ch = rest / 9;
  int c = ch * 32 + ((l >> 4) << 3) + j;
  int o = nt * 16 + (l & 15);
  float v = (o < OREAL) ? w[((size_t)o * CIN + c) * 9 + tap] : 0.f;
  bp[i] = f2bf(v);
}

// ---------------- fused (deformable) conv via MFMA implicit GEMM ------------
// Tile: 64 pixels (8x8) x OPAD outputs, K = CIN*9 in chunks of 32ch*9tap=288.
// A (sampled/im2col) staged in LDS bf16 (XOR-swizzled), B from prepacked global.
template <int CIN, int OPAD, int OREAL, bool DEFORM>
__global__ __launch_bounds__(256) void dcn_mfma(const u16* __restrict__ xt,
                                                const float* __restrict__ om,
                                                const float* __restrict__ boff,
                                                const u16* __restrict__ bpack,
                                                const float* __restrict__ bias,
                                                float* __restrict__ y) {
  constexpr int NCH = CIN / 32;
  constexpr int NTILES = OPAD / 16;
  constexpr int WN = (OPAD >= 64) ? 4 : 1;  // waves along N
  constexpr int NT = NTILES / WN;           // n-frags per wave
  constexpr int MT = (WN == 4) ? 4 : 1;     // m-frags per wave

  extern __shared__ char lds[];
  u16* As = (u16*)lds;  // [64][288] swizzled
  int* pAddr = (int*)(lds + 64 * 288 * 2);
  float* pWgt = (float*)(lds + 64 * 288 * 2 + 64 * 9 * 4 * 4);

  const int tid = threadIdx.x;
  const int lane = tid & 63;
  const int wv = tid >> 6;
  const int tile = blockIdx.x, b = blockIdx.y;
  const int h0 = (tile >> 4) << 3, w0 = (tile & 15) << 3;
  const u16* xb = xt + (size_t)b * kHW * CIN;

  if (DEFORM) {
    for (int idx = tid; idx < 576; idx += 256) {
      int px = idx / 9, tap = idx - px * 9;
      int h = h0 + (px >> 3), w = w0 + (px & 7);
      const float* omb = om + ((size_t)b * 27) * kHW + h * kW + w;
      float offy = omb[(size_t)tap * kHW] + boff[tap];
      float offx = omb[(size_t)(9 + tap) * kHW] + boff[9 + tap];
      float ml = omb[(size_t)(18 + tap) * kHW] + boff[18 + tap];
      float mask = 1.f / (1.f + expf(-ml));
      float py = (float)(h + tap / 3 - 1) + offy;
      float qx = (float)(w + tap % 3 - 1) + offx;
      float fy = floorf(py), fx = floorf(qx);
      float ly = py - fy, lx = qx - fx;
      int yi = (int)fy, xi = (int)fx;
      bool vy0 = (yi >= 0) & (yi < kH), vy1 = (yi + 1 >= 0) & (yi + 1 < kH);
      bool vx0 = (xi >= 0) & (xi < kW), vx1 = (xi + 1 >= 0) & (xi + 1 < kW);
      int y0c = min(max(yi, 0), kH - 1), y1c = min(max(yi + 1, 0), kH - 1);
      int x0c = min(max(xi, 0), kW - 1), x1c = min(max(xi + 1, 0), kW - 1);
      int e = (px * 9 + tap) * 4;
      pAddr[e + 0] = (y0c * kW + x0c) * CIN;
      pAddr[e + 1] = (y0c * kW + x1c) * CIN;
      pAddr[e + 2] = (y1c * kW + x0c) * CIN;
      pAddr[e + 3] = (y1c * kW + x1c) * CIN;
      pWgt[e + 0] = (vy0 && vx0) ? (1.f - ly) * (1.f - lx) * mask : 0.f;
      pWgt[e + 1] = (vy0 && vx1) ? (1.f - ly) * lx * mask : 0.f;
      pWgt[e + 2] = (vy1 && vx0) ? ly * (1.f - lx) * mask : 0.f;
      pWgt[e + 3] = (vy1 && vx1) ? ly * lx * mask : 0.f;
    }
  }

  f32x4 acc[MT][NT];
#pragma unroll
  for (int m = 0; m < MT; m++)
#pragma unroll
    for (int n = 0; n < NT; n++) acc[m][n] = (f32x4){0.f, 0.f, 0.f, 0.f};

  const int spx = tid >> 2, scg = tid & 3;  // sampling: pixel, channel-group
  const int sh = h0 + (spx >> 3), sw = w0 + (spx & 7);

  for (int ch = 0; ch < NCH; ch++) {
    __syncthreads();
    // ---- stage A-tile (sampled or im2col) into LDS ----
    const int coff = ch * 32 + scg * 8;
    if (DEFORM) {
      const int* ap = pAddr + spx * 36;
      const float* wp = pWgt + spx * 36;
#pragma unroll
      for (int tap = 0; tap < 9; tap++) {
        bf16x8 v0 = *reinterpret_cast<const bf16x8*>(xb + ap[tap * 4 + 0] + coff);
        bf16x8 v1 = *reinterpret_cast<const bf16x8*>(xb + ap[tap * 4 + 1] + coff);
        bf16x8 v2 = *reinterpret_cast<const bf16x8*>(xb + ap[tap * 4 + 2] + coff);
        bf16x8 v3 = *reinterpret_cast<const bf16x8*>(xb + ap[tap * 4 + 3] + coff);
        float g0 = wp[tap * 4 + 0], g1 = wp[tap * 4 + 1];
        float g2 = wp[tap * 4 + 2], g3 = wp[tap * 4 + 3];
        bf16x8 outv;
#pragma unroll
        for (int j = 0; j < 8; j++) {
          float s = g0 * bf2f(v0[j]) + g1 * bf2f(v1[j]) + g2 * bf2f(v2[j]) +
                    g3 * bf2f(v3[j]);
          outv[j] = (short)f2bf(s);
        }
        int byte = (spx * 576 + tap * 64 + scg * 16) ^ ((spx & 7) << 4);
        *reinterpret_cast<bf16x8*>(lds + byte) = outv;
      }
    } else {
#pragma unroll
      for (int tap = 0; tap < 9; tap++) {
        int yy = sh + tap / 3 - 1, xx = sw + tap % 3 - 1;
        bf16x8 v = (bf16x8){0, 0, 0, 0, 0, 0, 0, 0};
        if (yy >= 0 && yy < kH && xx >= 0 && xx < kW)
          v = *reinterpret_cast<const bf16x8*>(xb + (yy * kW + xx) * CIN + coff);
        int byte = (spx * 576 + tap * 64 + scg * 16) ^ ((spx & 7) << 4);
        *reinterpret_cast<bf16x8*>(lds + byte) = v;
      }
    }
    __syncthreads();
    // ---- MFMA over the 9 k-slices of this chunk ----
#pragma unroll
    for (int tap = 0; tap < 9; tap++) {
      bf16x8 af[MT];
#pragma unroll
      for (int m = 0; m < MT; m++) {
        int row = (WN == 4 ? m * 16 : wv * 16) + (lane & 15);
        int byte = (row * 576 + tap * 64 + ((lane >> 4) << 4)) ^ ((row & 7) << 4);
        af[m] = *reinterpret_cast<const bf16x8*>(lds + byte);
      }
#pragma unroll
      for (int nt = 0; nt < NT; nt++) {
        int ntg = (WN == 4) ? wv * NT + nt : nt;
        const u16* bp =
            bpack + ((((size_t)(ch * 9 + tap)) * NTILES + ntg) * 64 + lane) * 8;
        bf16x8 bfr = *reinterpret_cast<const bf16x8*>(bp);
#pragma unroll
        for (int m = 0; m < MT; m++)
          acc[m][nt] =
              __builtin_amdgcn_mfma_f32_16x16x32_bf16(af[m], bfr, acc[m][nt], 0, 0, 0);
      }
    }
  }

  // ---- epilogue: D layout col=lane&15, row=4*(lane>>4)+r ----
#pragma unroll
  for (int m = 0; m < MT; m++) {
#pragma unroll
    for (int nt = 0; nt < NT; nt++) {
      int o = ((WN == 4) ? wv * NT + nt : nt) * 16 + (lane & 15);
      if (OREAL < OPAD && o >= OREAL) continue;
      float bb = bias ? bias[o] : 0.f;
#pragma unroll
      for (int r = 0; r < 4; r++) {
        int row = (WN == 4 ? m * 16 : wv * 16) + ((lane >> 4) << 2) + r;
        int h = h0 + (row >> 3), w = w0 + (row & 7);
        y[((size_t)(b * OREAL + o)) * kHW + h * kW + w] = acc[m][nt][r] + bb;
      }
    }
  }
}

// ---------------- BN stats (one block per channel) ----------------
__global__ __launch_bounds__(256) void bn_stats(const float* __restrict__ y,
                                                const float* __restrict__ g,
                                                const float* __restrict__ be,
                                                float* __restrict__ ss, int C) {
  const int c = blockIdx.x;
  float s = 0.f, s2 = 0.f;
  for (int b = 0; b < kB; b++) {
    const float4* p = (const float4*)(y + ((size_t)(b * C + c)) * kHW);
    for (int i = threadIdx.x; i < kHW / 4; i += 256) {
      float4 v = p[i];
      s += v.x + v.y + v.z + v.w;
      s2 += v.x * v.x + v.y * v.y + v.z * v.z + v.w * v.w;
    }
  }
#pragma unroll
  for (int o = 32; o > 0; o >>= 1) {
    s += __shfl_down(s, o, 64);
    s2 += __shfl_down(s2, o, 64);
  }
  __shared__ float red[8];
  int lane = threadIdx.x & 63, wid = threadIdx.x >> 6;
  if (lane == 0) {
    red[wid] = s;
    red[4 + wid] = s2;
  }
  __syncthreads();
  if (threadIdx.x == 0) {
    float S = red[0] + red[1] + red[2] + red[3];
    float S2 = red[4] + red[5] + red[6] + red[7];
    const float inv = 1.f / (float)(kB * kHW);
    float mu = S * inv;
    float var = S2 * inv - mu * mu;
    float sc = g[c] * rsqrtf(var + 1e-5f);
    ss[2 * c] = sc;
    ss[2 * c + 1] = be[c] - mu * sc;
  }
}

// ---------------- BN apply + ReLU (final, NCHW in-place) ----------------
__global__ __launch_bounds__(256) void bn_apply(const float* __restrict__ y,
                                                const float* __restrict__ ss,
                                                float* __restrict__ out, int C,
                                                int total4) {
  int idx = blockIdx.x * 256 + threadIdx.x;
  int stride = gridDim.x * 256;
  for (int i = idx; i < total4; i += stride) {
    int c = (i >> 12) % C;
    float sc = ss[2 * c], shf = ss[2 * c + 1];
    float4 v = ((const float4*)y)[i];
    v.x = fmaxf(fmaf(v.x, sc, shf), 0.f);
    v.y = fmaxf(fmaf(v.y, sc, shf), 0.f);
    v.z = fmaxf(fmaf(v.z, sc, shf), 0.f);
    v.w = fmaxf(fmaf(v.w, sc, shf), 0.f);
    ((float4*)out)[i] = v;
  }
}

// ---------------- launch ----------------
extern "C" void kernel_launch(void* const* d_in, const int* in_sizes, int n_in,
                              void* d_out, int out_size, void* d_ws, size_t ws_size,
                              hipStream_t stream) {
  const float* x      = (const float*)d_in[0];
  const float* w_off1 = (const float*)d_in[1];
  const float* b_off1 = (const float*)d_in[2];
  const float* w1     = (const float*)d_in[3];
  const float* b1     = (const float*)d_in[4];
  const float* g1     = (const float*)d_in[5];
  const float* be1    = (const float*)d_in[6];
  const float* w_off2 = (const float*)d_in[7];
  const float* b_off2 = (const float*)d_in[8];
  const float* w2     = (const float*)d_in[9];
  const float* b2     = (const float*)d_in[10];
  const float* g2     = (const float*)d_in[11];
  const float* be2    = (const float*)d_in[12];

  char* ws = (char*)d_ws;
  const size_t XT_OFF  = 0;                        // xt1 (33.5MB); xt2 aliases
  const size_t XT_SZ   = (size_t)kB * kHW * kC1 * 2;
  const size_t OM_OFF  = XT_OFF + XT_SZ;           // 7MB
  const size_t OM_SZ   = (size_t)27 * kB * kHW * 4;
  const size_t BPO1_OFF = OM_OFF + OM_SZ;          // 147KB
  const size_t BPO1_SZ  = (size_t)(kC1 / 32) * 9 * 2 * 64 * 8 * 2;
  const size_t BP1_OFF = BPO1_OFF + BPO1_SZ;       // 590KB
  const size_t BP1_SZ  = (size_t)(kC1 / 32) * 9 * (kM / 16) * 64 * 8 * 2;
  const size_t BPO2_OFF = BP1_OFF + BP1_SZ;        // 74KB
  const size_t BPO2_SZ  = (size_t)(kM / 32) * 9 * 2 * 64 * 8 * 2;
  const size_t BP2_OFF = BPO2_OFF + BPO2_SZ;       // 1.18MB
  const size_t BP2_SZ  = (size_t)(kM / 32) * 9 * (kC2 / 16) * 64 * 8 * 2;
  const size_t SS_OFF  = BP2_OFF + BP2_SZ;

  u16* xt1  = (u16*)(ws + XT_OFF);
  u16* xt2  = (u16*)(ws + XT_OFF);  // alias: xt1 dead before xt2 written
  float* om = (float*)(ws + OM_OFF);
  u16* bpo1 = (u16*)(ws + BPO1_OFF);
  u16* bp1  = (u16*)(ws + BP1_OFF);
  u16* bpo2 = (u16*)(ws + BPO2_OFF);
  u16* bp2  = (u16*)(ws + BP2_OFF);
  float* ssb = (float*)(ws + SS_OFF);
  float* y1 = (float*)d_out;   // 33.5MB of 67MB
  float* y2 = (float*)d_out;

  const int LDS_DEF = 64 * 288 * 2 + 64 * 9 * 4 * 8;  // 55296
  const int LDS_IMC = 64 * 288 * 2;                   // 36864

  // ---------- layer 1 ----------
  to_nhwc<false><<<256, 256, 0, stream>>>(x, nullptr, xt1, kC1);
  prep_bpack<<<(8 * 9 * 2 * 512 + 255) / 256, 256, 0, stream>>>(w_off1, bpo1, kC1, 32, 27);
  prep_bpack<<<(8 * 9 * 8 * 512 + 255) / 256, 256, 0, stream>>>(w1, bp1, kC1, kM, kM);
  dcn_mfma<kC1, 32, 27, false><<<dim3(256, kB), 256, LDS_IMC, stream>>>(
      xt1, nullptr, nullptr, bpo1, nullptr, om);
  dcn_mfma<kC1, kM, kM, true><<<dim3(256, kB), 256, LDS_DEF, stream>>>(
      xt1, om, b_off1, bp1, b1, y1);
  bn_stats<<<kM, 256, 0, stream>>>(y1, g1, be1, ssb, kM);
  to_nhwc<true><<<256, 256, 0, stream>>>(y1, ssb, xt2, kM);

  // ---------- layer 2 ----------
  prep_bpack<<<(4 * 9 * 2 * 512 + 255) / 256, 256, 0, stream>>>(w_off2, bpo2, kM, 32, 27);
  prep_bpack<<<(4 * 9 * 16 * 512 + 255) / 256, 256, 0, stream>>>(w2, bp2, kM, kC2, kC2);
  dcn_mfma<kM, 32, 27, false><<<dim3(256, kB), 256, LDS_IMC, stream>>>(
      xt2, nullptr, nullptr, bpo2, nullptr, om);
  dcn_mfma<kM, kC2, kC2, true><<<dim3(256, kB), 256, LDS_DEF, stream>>>(
      xt2, om, b_off2, bp2, b2, y2);
  bn_stats<<<kC2, 256, 0, stream>>>(y2, g2, be2, ssb, kC2);
  bn_apply<<<2048, 256, 0, stream>>>(y2, ssb, (float*)d_out, kC2, kB * kC2 * kHW / 4);
}